// Round 9
// baseline (215.453 us; speedup 1.0000x reference)
//
#include <hip/hip_runtime.h>

typedef _Float16 half_t;
typedef __attribute__((ext_vector_type(8))) _Float16 f16x8;  // 8 f16 = 4 VGPRs
typedef __attribute__((ext_vector_type(4))) float f32x4;

static constexpr int Bsz = 4096;   // batch
static constexpr int INs = 512;    // input features
static constexpr int Hs  = 1024;   // hidden
static constexpr int BM  = 128;    // batch rows per block
static constexpr int BH  = 32;     // h-cols per block (x4 gates = 128 eff cols)
static constexpr int BK  = 64;     // K-tile
static constexpr int NIT = INs / BK + Hs / BK;   // 8 + 16 = 24 K-iters

__device__ __forceinline__ float sigm(float x) {
  return 1.0f / (1.0f + __expf(-x));
}
__device__ __forceinline__ float tanh_fast(float x) {
  const float e = __expf(2.0f * x);
  return 1.0f - 2.0f / (e + 1.0f);
}

// Single fused kernel: gates = X*Wxh^T + hx*Whh^T + b via fp16 MFMA
// (fp32 accum), fp32->fp16 conversion inline during LDS staging, time-gate
// + LSTM epilogue in fp32 (np op order).
// 4 blocks/CU co-resident (grid = 1024 = 4 x 256 CUs, 32 KB LDS, <=128 VGPR):
// cross-block wave overlap (m114) fills barrier stalls; staging VALU (cvt)
// overlaps other blocks' MFMA.
// Wave tiling 2x2: wave (wr,wc) -> rows wr*64+mt*16, eff-cols wc*64+nt*16.
// Eff-col c -> gate (c>>4)&3, h = h0 + (c>>6)*16 + (c&15): all four gates of
// one (b,h) sit in the same lane across acc[mt][0..3].
__global__ __launch_bounds__(256, 4)
void plstm_fused(const float* __restrict__ xin,   // [B,IN]
                 const float* __restrict__ timep, // [B]
                 const float* __restrict__ hxp,   // [B,H]
                 const float* __restrict__ cxp,   // [B,H]
                 const float* __restrict__ wxh,   // [4H,IN]
                 const float* __restrict__ biasp, // [4H]
                 const float* __restrict__ whh,   // [4H,H]
                 const float* __restrict__ taup,  // [H]
                 const float* __restrict__ sp,    // [H]
                 const float* __restrict__ alphap,// [1]
                 const float* __restrict__ rhop,  // [1]
                 float* __restrict__ outp)        // [2,B,H] = hy ; cy
{
  // XOR-swizzled 16B-chunk layout: slot (row e, c8) holds global chunk c8^(e&7).
  __shared__ half_t As[BM * BK];    // 16 KB
  __shared__ half_t Bs[BM * BK];    // 16 KB

  const int tid  = threadIdx.x;
  const int w    = tid >> 6;
  const int lane = tid & 63;
  const int l15  = lane & 15;
  const int grp  = lane >> 4;
  const int wr   = w >> 1;
  const int wc   = w & 1;

  const int m0 = blockIdx.x * BM;
  const int h0 = blockIdx.y * BH;

  f32x4 acc[4][4] = {};              // [m-subtile][gate]

  const int ldr = tid >> 3;          // 0..31
  const int ldc = tid & 7;           // 16B chunk col 0..7

  for (int it = 0; it < NIT; ++it) {
    const bool p1 = it >= INs / BK;
    const float* Ap = p1 ? hxp : xin;
    const float* Wp = p1 ? whh : wxh;
    const int Ka = p1 ? Hs : INs;
    const int k0 = (p1 ? (it - INs / BK) : it) * BK;
    #pragma unroll
    for (int i = 0; i < 4; ++i) {
      const int e    = i * 32 + ldr;
      const int gc8  = ldc ^ (e & 7);            // swizzle on global side
      const int wrow = ((e >> 4) & 3) * Hs + h0 + ((e >> 6) << 4) + (e & 15);
      const float* ga = Ap + (size_t)(m0 + e) * Ka + (k0 + gc8 * 8);
      const f32x4 a0 = *(const f32x4*)ga, a1 = *(const f32x4*)(ga + 4);
      f16x8 pa;
      pa[0]=(half_t)a0[0]; pa[1]=(half_t)a0[1]; pa[2]=(half_t)a0[2]; pa[3]=(half_t)a0[3];
      pa[4]=(half_t)a1[0]; pa[5]=(half_t)a1[1]; pa[6]=(half_t)a1[2]; pa[7]=(half_t)a1[3];
      *(f16x8*)(As + (e * 8 + ldc) * 8) = pa;
      const float* gw = Wp + (size_t)wrow * Ka + (k0 + gc8 * 8);
      const f32x4 b0 = *(const f32x4*)gw, b1 = *(const f32x4*)(gw + 4);
      f16x8 pb;
      pb[0]=(half_t)b0[0]; pb[1]=(half_t)b0[1]; pb[2]=(half_t)b0[2]; pb[3]=(half_t)b0[3];
      pb[4]=(half_t)b1[0]; pb[5]=(half_t)b1[1]; pb[6]=(half_t)b1[2]; pb[7]=(half_t)b1[3];
      *(f16x8*)(Bs + (e * 8 + ldc) * 8) = pb;
    }
    __syncthreads();

    #pragma unroll
    for (int kk = 0; kk < 2; ++kk) {
      const int c8x = kk * 4 + grp;
      f16x8 af[4], bfr[4];
      #pragma unroll
      for (int mt = 0; mt < 4; ++mt) {
        const int e = wr * 64 + mt * 16 + l15;   // e&7 == l15&7
        af[mt] = *(const f16x8*)(As + (e * 8 + (c8x ^ (l15 & 7))) * 8);
      }
      #pragma unroll
      for (int nt = 0; nt < 4; ++nt) {
        const int e = wc * 64 + nt * 16 + l15;
        bfr[nt] = *(const f16x8*)(Bs + (e * 8 + (c8x ^ (l15 & 7))) * 8);
      }
      #pragma unroll
      for (int mt = 0; mt < 4; ++mt)
        #pragma unroll
        for (int nt = 0; nt < 4; ++nt)
          acc[mt][nt] = __builtin_amdgcn_mfma_f32_16x16x32_f16(
              af[mt], bfr[nt], acc[mt][nt], 0, 0, 0);
    }
    __syncthreads();
  }

  // ---- fused epilogue: each thread owns ONE h and 16 batch rows ----
  const int h = h0 + wc * 16 + l15;
  const float bi  = biasp[h];
  const float bfv = biasp[Hs + h];
  const float bg  = biasp[2 * Hs + h];
  const float bo  = biasp[3 * Hs + h];
  const float sv = sp[h], tauv = taup[h];
  const float alphav = alphap[0], rhov = rhop[0], rh = 0.5f * rhov;

  #pragma unroll
  for (int mt = 0; mt < 4; ++mt) {
    #pragma unroll
    for (int r = 0; r < 4; ++r) {
      // C/D layout (m89-verified): col = lane&15, row = grp*4 + reg
      const int brow = m0 + wr * 64 + mt * 16 + grp * 4 + r;
      const float tv = timep[brow];
      const float phi = fmodf(tv - sv, tauv) / tauv;
      float kv;
      if (phi < rh)        kv = (2.0f * phi) / rhov;
      else if (phi < rhov) kv = 2.0f - (2.0f * phi) / rhov;
      else                 kv = alphav * phi;

      const float iv = acc[mt][0][r] + bi;
      const float fv = acc[mt][1][r] + bfv;
      const float gv = acc[mt][2][r] + bg;
      const float ov = acc[mt][3][r] + bo;
      const float cxv = cxp[(size_t)brow * Hs + h];
      const float ft = sigm(fv + 1.0f - kv);
      const float it2 = sigm(iv) * kv;
      const float gt = tanh_fast(gv) * kv;
      const float ot = sigm(ov) * kv;
      const float cy = ft * cxv + it2 * gt;
      const float hy = ot * tanh_fast(cy);

      outp[(size_t)brow * Hs + h] = hy;
      outp[(size_t)Bsz * Hs + (size_t)brow * Hs + h] = cy;
    }
  }
}

extern "C" void kernel_launch(void* const* d_in, const int* in_sizes, int n_in,
                              void* d_out, int out_size, void* d_ws, size_t ws_size,
                              hipStream_t stream) {
  (void)in_sizes; (void)n_in; (void)out_size; (void)d_ws; (void)ws_size;
  dim3 grid(Bsz / BM, Hs / BH);   // 32 x 32 = 1024 blocks = 4 per CU
  plstm_fused<<<grid, 256, 0, stream>>>(
      (const float*)d_in[0], (const float*)d_in[1], (const float*)d_in[2],
      (const float*)d_in[3], (const float*)d_in[4], (const float*)d_in[5],
      (const float*)d_in[6], (const float*)d_in[7], (const float*)d_in[8],
      (const float*)d_in[9], (const float*)d_in[10],
      (float*)d_out);
}